// Round 4
// baseline (777.298 us; speedup 1.0000x reference)
//
#include <hip/hip_runtime.h>
#include <stdint.h>

#define N_NODES 8192
#define IN_F    512
#define OUT_F   256
#define ALPHA   0.2f

typedef __attribute__((ext_vector_type(8))) short bf16x8;
typedef __attribute__((ext_vector_type(4))) float f32x4;

__device__ __forceinline__ uint32_t f32_to_bf16(float f) {
    union { float f; uint32_t u; } v; v.f = f;
    uint32_t u = v.u;
    return (u + 0x7fffu + ((u >> 16) & 1u)) >> 16;   // RNE
}

// ---------------------------------------------------------------------------
// K0: w1 = W^T a1, w2 = W^T a2  (w12[0:512]=w1, w12[512:1024]=w2)
// ---------------------------------------------------------------------------
__global__ __launch_bounds__(256) void k0_wvec(
    const float* __restrict__ W, const float* __restrict__ a_vec,
    float* __restrict__ w12)
{
    const int t  = threadIdx.x;
    const int nb = blockIdx.x * 8;
    float a1lo = 0.f, a1hi = 0.f, a2lo = 0.f, a2hi = 0.f;
    #pragma unroll
    for (int q = 0; q < 8; q++) {
        int n = nb + q;
        float lo = W[(size_t)n * IN_F + t];
        float hi = W[(size_t)n * IN_F + t + 256];
        float a1 = a_vec[n], a2 = a_vec[OUT_F + n];
        a1lo = fmaf(lo, a1, a1lo); a1hi = fmaf(hi, a1, a1hi);
        a2lo = fmaf(lo, a2, a2lo); a2hi = fmaf(hi, a2, a2hi);
    }
    atomicAdd(&w12[t], a1lo);       atomicAdd(&w12[t + 256], a1hi);
    atomicAdd(&w12[512 + t], a2lo); atomicAdd(&w12[512 + t + 256], a2hi);
}

// ---------------------------------------------------------------------------
// Ks: s_src[i] = h[i] . w1 ; s_dst[i] = h[i] . w2   (1 wave per row)
// ---------------------------------------------------------------------------
__global__ __launch_bounds__(256) void ks_svec(
    const float* __restrict__ h, const float* __restrict__ w12,
    float* __restrict__ s_src, float* __restrict__ s_dst)
{
    __shared__ float sw[1024];
    const int t = threadIdx.x;
    #pragma unroll
    for (int q = 0; q < 4; q++) sw[q * 256 + t] = w12[q * 256 + t];
    __syncthreads();
    const int w = t >> 6, ln = t & 63;
    const int i = blockIdx.x * 4 + w;
    const float* hr = h + (size_t)i * IN_F + ln * 8;
    float4 h0 = *(const float4*)hr;
    float4 h1 = *(const float4*)(hr + 4);
    const float* w1 = sw + ln * 8;
    const float* w2 = sw + 512 + ln * 8;
    float v1 = h0.x*w1[0] + h0.y*w1[1] + h0.z*w1[2] + h0.w*w1[3]
             + h1.x*w1[4] + h1.y*w1[5] + h1.z*w1[6] + h1.w*w1[7];
    float v2 = h0.x*w2[0] + h0.y*w2[1] + h0.z*w2[2] + h0.w*w2[3]
             + h1.x*w2[4] + h1.y*w2[5] + h1.z*w2[6] + h1.w*w2[7];
    #pragma unroll
    for (int off = 32; off >= 1; off >>= 1) {
        v1 += __shfl_xor(v1, off, 64);
        v2 += __shfl_xor(v2, off, 64);
    }
    if (ln == 0) { s_src[i] = v1; s_dst[i] = v2; }
}

// ---------------------------------------------------------------------------
// K1: Wh = h @ W^T (fp32) -> whf bf16 MFMA-B-frag-major.
// chunk c = (j>>5)*16 + (n>>4); lane = (n&15) + ((j>>3)&3)*16, elem = j&7.
// Epilogue: repack via LDS, then coalesced uint4 stores (fixes scattered 2B).
// ---------------------------------------------------------------------------
__global__ __launch_bounds__(256) void k1_wh_pack(
    const float* __restrict__ h, const float* __restrict__ W,
    uint16_t* __restrict__ whf)
{
    const int n0 = blockIdx.x * 64, i0 = blockIdx.y * 64;
    const int t  = threadIdx.x;
    const int tn = t & 15, tm = t >> 4;

    __shared__ float As[32][65];
    __shared__ float Bs[32][65];
    __shared__ uint16_t stg[8192];    // 16 KB bf16 repack staging

    float acc[4][4];
    #pragma unroll
    for (int i = 0; i < 4; i++)
        #pragma unroll
        for (int j = 0; j < 4; j++) acc[i][j] = 0.f;

    for (int k0 = 0; k0 < IN_F; k0 += 32) {
        __syncthreads();
        #pragma unroll
        for (int q = 0; q < 2; q++) {
            int u   = q * 256 + t;
            int row = u >> 3;
            int kf  = (u & 7) * 4;
            float4 va = *(const float4*)&h[(size_t)(i0 + row) * IN_F + k0 + kf];
            As[kf + 0][row] = va.x; As[kf + 1][row] = va.y;
            As[kf + 2][row] = va.z; As[kf + 3][row] = va.w;
            float4 vb = *(const float4*)&W[(size_t)(n0 + row) * IN_F + k0 + kf];
            Bs[kf + 0][row] = vb.x; Bs[kf + 1][row] = vb.y;
            Bs[kf + 2][row] = vb.z; Bs[kf + 3][row] = vb.w;
        }
        __syncthreads();
        #pragma unroll
        for (int kk = 0; kk < 32; kk++) {
            float a[4], b[4];
            *(float4*)a = *(const float4*)&As[kk][tm * 4];
            *(float4*)b = *(const float4*)&Bs[kk][tn * 4];
            #pragma unroll
            for (int i = 0; i < 4; i++)
                #pragma unroll
                for (int j = 0; j < 4; j++) acc[i][j] = fmaf(a[i], b[j], acc[i][j]);
        }
    }

    // repack to frag layout in LDS (local 64x64 tile -> 8 chunks of 1KB)
    #pragma unroll
    for (int ii = 0; ii < 4; ii++) {
        int gr = tm * 4 + ii;                 // local row (j of att)
        int lr = (gr >> 3) & 3, jj = gr & 7, ckl = gr >> 5;
        #pragma unroll
        for (int jn = 0; jn < 4; jn++) {
            int gc = tn * 4 + jn;             // local col (n)
            int lc = ckl * 4 + (gc >> 4);
            int lane = (gc & 15) + lr * 16;
            stg[lc * 512 + lane * 8 + jj] = (uint16_t)f32_to_bf16(acc[ii][jn]);
        }
    }
    __syncthreads();
    {   // coalesced copy-out: 2 x 4KB contiguous regions
        int half = t >> 7, idx = t & 127;
        int c0 = ((i0 >> 5) + half) * 16 + (n0 >> 4);
        uint4* g4 = (uint4*)whf + (size_t)c0 * 64 + idx * 2;
        const uint4* l4 = (const uint4*)stg + half * 256 + idx * 2;
        g4[0] = l4[0]; g4[1] = l4[1];
    }
}

// ---------------------------------------------------------------------------
// K2: adjacency -> phase-interleaved bitmask + softmax denominators l[i].
// mask word (i, jb, ph) bit b  <->  adj[i][jb*256 + b*4 + ph] > 0.
// nontemporal adj loads (read-once, don't pollute L2).
// ---------------------------------------------------------------------------
__global__ __launch_bounds__(256) void k2_mask_l(
    const float* __restrict__ adj, const float* __restrict__ s_src,
    const float* __restrict__ s_dst, uint64_t* __restrict__ mask,
    float* __restrict__ l_out)
{
    const int i = blockIdx.x;
    const int t = threadIdx.x, w = t >> 6, ln = t & 63;
    const float si = s_src[i];
    const f32x4* rowv = (const f32x4*)(adj + (size_t)i * N_NODES);
    const float4* sdv = (const float4*)s_dst;
    float acc = 0.f;
    #pragma unroll 2
    for (int it = 0; it < 8; it++) {
        int jb = it * 4 + w;
        int v4 = jb * 64 + ln;
        f32x4 a   = __builtin_nontemporal_load(rowv + v4);
        float4 sd = sdv[v4];
        uint64_t b0 = __ballot(a.x > 0.f);
        uint64_t b1 = __ballot(a.y > 0.f);
        uint64_t b2 = __ballot(a.z > 0.f);
        uint64_t b3 = __ballot(a.w > 0.f);
        if (ln == 0) {
            uint64_t* mw = mask + (size_t)i * 128 + jb * 4;
            mw[0] = b0; mw[1] = b1; mw[2] = b2; mw[3] = b3;
        }
        float x, e;
        x = si + sd.x; e = fmaxf(x, ALPHA * x); if (a.x > 0.f) acc += __expf(e);
        x = si + sd.y; e = fmaxf(x, ALPHA * x); if (a.y > 0.f) acc += __expf(e);
        x = si + sd.z; e = fmaxf(x, ALPHA * x); if (a.z > 0.f) acc += __expf(e);
        x = si + sd.w; e = fmaxf(x, ALPHA * x); if (a.w > 0.f) acc += __expf(e);
    }
    #pragma unroll
    for (int off = 32; off >= 1; off >>= 1) acc += __shfl_xor(acc, off, 64);
    __shared__ float red[4];
    if (ln == 0) red[w] = acc;
    __syncthreads();
    if (t == 0) l_out[i] = (red[0] + red[1]) + (red[2] + red[3]);
}

// ---------------------------------------------------------------------------
// K3: fused attention-write + (attention @ Wh) bf16 MFMA GEMM.
// BARRIER-FREE / LDS-FREE: grid (128 rb, 4 jc), 256 thr. Block: 64 rows x
// 2048 j. Wave w owns a 16-row x 256-col slab (16 ntiles, acc 64 VGPR).
// Per iter (BK=64): A-frags in registers from mask/s_dst (L2-hit loads),
// B-frags direct global->VGPR from whf (L2-resident, 4 waves share 32KB/iter
// via L1), 32 MFMA, nontemporal att store — stores never drain at a barrier.
// ---------------------------------------------------------------------------
__global__ __launch_bounds__(256, 3) void k3_att_gemm(
    const uint64_t* __restrict__ mask, const float* __restrict__ s_src,
    const float* __restrict__ s_dst, const float* __restrict__ l_in,
    const uint16_t* __restrict__ whf, float* __restrict__ att_out,
    float* __restrict__ partial)
{
    const int rb = blockIdx.x, jc = blockIdx.y;
    const int i0 = rb * 64, jbase = jc * 2048;
    const int t = threadIdx.x, w = t >> 6, ln = t & 63;
    const int m   = ln & 15;            // row within wave slab
    const int kof = (ln >> 4) * 8;      // k-offset within BK=32

    const int row = i0 + w * 16 + m;
    const float sim = s_src[row];
    const float il  = 1.0f / l_in[row];
    const uint64_t* mrow = mask + (size_t)row * 128 + jc * 32;
    float* arow = att_out + (size_t)row * N_NODES;

    f32x4 acc[16];
    #pragma unroll
    for (int b = 0; b < 16; b++) acc[b] = (f32x4){0.f, 0.f, 0.f, 0.f};

    uint64_t mwv[4];
    for (int it = 0; it < 32; it++) {
        const int J0 = jbase + it * 64;
        if ((it & 3) == 0) {            // one mask word covers 256 j = 4 iters
            const ulonglong2* mp = (const ulonglong2*)(mrow + (it >> 2) * 4);
            ulonglong2 m01 = mp[0], m23 = mp[1];
            mwv[0] = m01.x; mwv[1] = m01.y; mwv[2] = m23.x; mwv[3] = m23.y;
        }
        float p[2][8];
        #pragma unroll
        for (int ks = 0; ks < 2; ks++) {
            float4 s0 = *(const float4*)(s_dst + J0 + ks * 32 + kof);
            float4 s1 = *(const float4*)(s_dst + J0 + ks * 32 + kof + 4);
            float sdv[8] = {s0.x, s0.y, s0.z, s0.w, s1.x, s1.y, s1.z, s1.w};
            int bb = ((it & 3) << 4) + (ks << 3) + (kof >> 2);
            #pragma unroll
            for (int jj = 0; jj < 8; jj++) {
                float x  = sim + sdv[jj];
                float e  = fmaxf(x, ALPHA * x);
                float pe = __expf(e) * il;
                p[ks][jj] = ((mwv[jj & 3] >> (bb + (jj >> 2))) & 1ull) ? pe : 0.f;
            }
        }
        {   // att store: 32B contiguous per lane, never barrier-drained
            float* go = arow + J0 + kof;
            __builtin_nontemporal_store(*(f32x4*)&p[0][0], (f32x4*)go);
            __builtin_nontemporal_store(*(f32x4*)&p[0][4], (f32x4*)(go + 4));
            __builtin_nontemporal_store(*(f32x4*)&p[1][0], (f32x4*)(go + 32));
            __builtin_nontemporal_store(*(f32x4*)&p[1][4], (f32x4*)(go + 36));
        }
        #pragma unroll
        for (int ks = 0; ks < 2; ks++) {
            union { bf16x8 v; uint32_t u[4]; } pk;
            #pragma unroll
            for (int q = 0; q < 4; q++)
                pk.u[q] = f32_to_bf16(p[ks][2 * q]) | (f32_to_bf16(p[ks][2 * q + 1]) << 16);
            bf16x8 af = pk.v;
            const uint4* bsrc = (const uint4*)whf
                + ((size_t)((jbase + it * 64) >> 5) + ks) * 1024 + ln;
            #pragma unroll
            for (int nt = 0; nt < 16; nt++) {
                bf16x8 bfr;
                *(uint4*)&bfr = bsrc[nt * 64];
                acc[nt] = __builtin_amdgcn_mfma_f32_16x16x32_bf16(af, bfr, acc[nt], 0, 0, 0);
            }
        }
    }

    // epilogue: partial[jc][row][col]; C/D: col=lane&15, row=(lane>>4)*4+reg
    float* pbase = partial + (size_t)jc * ((size_t)N_NODES * OUT_F);
    int gr0 = i0 + w * 16 + (ln >> 4) * 4;
    #pragma unroll
    for (int nt = 0; nt < 16; nt++) {
        int gc = nt * 16 + m;
        #pragma unroll
        for (int r = 0; r < 4; r++)
            pbase[(size_t)(gr0 + r) * OUT_F + gc] = acc[nt][r];
    }
}

// ---------------------------------------------------------------------------
// K4: h_prime = sum of 4 split-K partials
// ---------------------------------------------------------------------------
__global__ __launch_bounds__(256) void k4_reduce(
    const float* __restrict__ partial, float* __restrict__ hp)
{
    const size_t S = (size_t)N_NODES * OUT_F;
    int idx = (blockIdx.x * 256 + threadIdx.x) * 4;
    float4 a = *(const float4*)(partial + idx);
    float4 b = *(const float4*)(partial + S + idx);
    float4 c = *(const float4*)(partial + 2 * S + idx);
    float4 d = *(const float4*)(partial + 3 * S + idx);
    float4 o;
    o.x = (a.x + b.x) + (c.x + d.x);
    o.y = (a.y + b.y) + (c.y + d.y);
    o.z = (a.z + b.z) + (c.z + d.z);
    o.w = (a.w + b.w) + (c.w + d.w);
    *(float4*)(hp + idx) = o;
}

extern "C" void kernel_launch(void* const* d_in, const int* in_sizes, int n_in,
                              void* d_out, int out_size, void* d_ws, size_t ws_size,
                              hipStream_t stream) {
    (void)in_sizes; (void)n_in; (void)out_size; (void)ws_size;
    const float* h     = (const float*)d_in[0];
    const float* adj   = (const float*)d_in[1];
    const float* W     = (const float*)d_in[2];
    const float* a_vec = (const float*)d_in[3];

    char* ws = (char*)d_ws;
    uint16_t* whf  = (uint16_t*)(ws);                          // 4 MB
    uint64_t* mask = (uint64_t*)(ws + ((size_t)4 << 20));      // 8 MB
    float* partial = (float*)(ws + ((size_t)12 << 20));        // 32 MB
    float* w12     = (float*)(ws + ((size_t)44 << 20));        // 4 KB
    float* s_src   = (float*)(ws + ((size_t)44 << 20) + 16384);
    float* s_dst   = (float*)(ws + ((size_t)44 << 20) + 16384 + 32768);
    float* l_buf   = (float*)(ws + ((size_t)44 << 20) + 16384 + 65536);

    float* hp  = (float*)d_out;
    float* att = hp + (size_t)N_NODES * OUT_F;

    (void)hipMemsetAsync(w12, 0, 4096, stream);
    k0_wvec<<<32, 256, 0, stream>>>(W, a_vec, w12);
    ks_svec<<<2048, 256, 0, stream>>>(h, w12, s_src, s_dst);
    k1_wh_pack<<<dim3(4, 128), 256, 0, stream>>>(h, W, whf);
    k2_mask_l<<<8192, 256, 0, stream>>>(adj, s_src, s_dst, mask, l_buf);
    k3_att_gemm<<<dim3(128, 4), 256, 0, stream>>>(mask, s_src, s_dst, l_buf, whf, att, partial);
    k4_reduce<<<2048, 256, 0, stream>>>(partial, hp);
}